// Round 7
// baseline (855.711 us; speedup 1.0000x reference)
//
#include <hip/hip_runtime.h>
#include <hip/hip_bf16.h>

using bf16 = __hip_bfloat16;
typedef __bf16 bfrag __attribute__((ext_vector_type(8)));
typedef float  ffrag __attribute__((ext_vector_type(4)));

// Problem: B=32, N=8, Q=1536, K=256, CELL=128, EMB=32. Inputs f32, outputs f32.
// workspace layout (bytes)
#define WS_EO    0         // emb_o bf16 [256 key][32 e]                16 KB
#define WS_W2T   16384     // Wq2^T bf16 [32 e][256 h]                  16 KB
#define WS_W1T   32768     // Wq1^T bf16 [256 h][32 in-pad] (+bias k15) 16 KB
#define WS_WA1T  49152     // Wa1^T bf16 [64 u][32 e]                    4 KB
#define WS_VBF   65536     // view_cell bf16 [256 bn][128 c][256 k]     16 MB (optional)

__device__ __forceinline__ float sigmoidf_(float x){ return 1.f/(1.f+__expf(-x)); }

__device__ __forceinline__ void relpose(const float* mo, const float* mq, float* o) {
  float a=mo[0],bb=mo[1],c=mo[2], d=mo[4],e=mo[5],f=mo[6], g=mo[8],h=mo[9],i9=mo[10];
  float A = e*i9-f*h, Bc = f*g-d*i9, C = d*h-e*g;
  float inv = 1.f/(a*A + bb*Bc + c*C);
  float r00=A*inv,  r01=(c*h-bb*i9)*inv, r02=(bb*f-c*e)*inv;
  float r10=Bc*inv, r11=(a*i9-c*g)*inv,  r12=(c*d-a*f)*inv;
  float r20=C*inv,  r21=(bb*g-a*h)*inv,  r22=(a*e-bb*d)*inv;
  float tx = mq[3]-mo[3], ty = mq[7]-mo[7], tz = mq[11]-mo[11];
  o[0]=r00*mq[0]+r01*mq[4]+r02*mq[8];  o[1]=r00*mq[1]+r01*mq[5]+r02*mq[9];
  o[2]=r00*mq[2]+r01*mq[6]+r02*mq[10]; o[3]=r00*tx+r01*ty+r02*tz;
  o[4]=r10*mq[0]+r11*mq[4]+r12*mq[8];  o[5]=r10*mq[1]+r11*mq[5]+r12*mq[9];
  o[6]=r10*mq[2]+r11*mq[6]+r12*mq[10]; o[7]=r10*tx+r11*ty+r12*tz;
  o[8]=r20*mq[0]+r21*mq[4]+r22*mq[8];  o[9]=r20*mq[1]+r21*mq[5]+r22*mq[9];
  o[10]=r20*mq[2]+r21*mq[6]+r22*mq[10]; o[11]=r20*tx+r21*ty+r22*tz;
}

__device__ __forceinline__ void quat7(const float* m, float* o) {
  float m00=m[0], m01=m[1], m02=m[2];
  float m10=m[4], m11=m[5], m12=m[6];
  float m20=m[8], m21=m[9], m22=m[10];
  float t,q0,q1,q2,q3;
  if (m22 < 0.f) {
    if (m00 > m11) { t=1.f+m00-m11-m22; q0=t;        q1=m01+m10; q2=m20+m02; q3=m12-m21; }
    else           { t=1.f-m00+m11-m22; q0=m01+m10; q1=t;        q2=m12+m21; q3=m20-m02; }
  } else {
    if (m00 < -m11){ t=1.f-m00-m11+m22; q0=m20+m02; q1=m12+m21; q2=t;        q3=m01-m10; }
    else           { t=1.f+m00+m11+m22; q0=m12-m21; q1=m20-m02; q2=m01-m10; q3=t;        }
  }
  float s = 0.5f / sqrtf(t);
  o[0]=m[3]; o[1]=m[7]; o[2]=m[11];
  o[3]=q0*s; o[4]=q1*s; o[5]=q2*s; o[6]=q3*s;
}

// ---------------- single prep kernel: vconv blocks + 5 parallel 1-block roles --------
__global__ void k_prep(const float* __restrict__ vc, bf16* __restrict__ vbf,
                       const float* __restrict__ pose_o, const float* __restrict__ pose_q,
                       const float* __restrict__ Wk1, const float* __restrict__ bk1,
                       const float* __restrict__ Wk2, const float* __restrict__ bk2,
                       const float* __restrict__ Wq1, const float* __restrict__ bq1,
                       const float* __restrict__ Wq2, const float* __restrict__ Wa1,
                       float* __restrict__ out_qo, float* __restrict__ out_qq,
                       bf16* __restrict__ ws_eo, bf16* __restrict__ ws_w2t,
                       bf16* __restrict__ ws_w1t, bf16* __restrict__ ws_wa1t,
                       int vblocks) {
  const int bid = blockIdx.x, tid = threadIdx.x;
  if (bid < vblocks) {   // view_cell f32 -> bf16
    int idx = (bid*256 + tid)*8;
    float4 a = *(const float4*)&vc[idx];
    float4 b = *(const float4*)&vc[idx+4];
    __bf16 o[8] __attribute__((aligned(16)));
    o[0]=(__bf16)a.x; o[1]=(__bf16)a.y; o[2]=(__bf16)a.z; o[3]=(__bf16)a.w;
    o[4]=(__bf16)b.x; o[5]=(__bf16)b.y; o[6]=(__bf16)b.z; o[7]=(__bf16)b.w;
    *(uint4*)&vbf[idx] = *(const uint4*)o;
    return;
  }
  const int role = bid - vblocks;
  if (role == 0) {          // quaternion outputs
    float mo[12];
    #pragma unroll
    for (int i=0;i<12;i++) mo[i] = pose_o[tid*12+i];
    float q7[7]; quat7(mo, q7);
    #pragma unroll
    for (int i=0;i<7;i++) out_qo[tid*7+i] = q7[i];
    if (tid < 32) {
      float mq[12];
      #pragma unroll
      for (int i=0;i<12;i++) mq[i] = pose_q[tid*12+i];
      float q7b[7]; quat7(mq, q7b);
      #pragma unroll
      for (int i=0;i<7;i++) out_qq[tid*7+i] = q7b[i];
    }
  } else if (role == 1) {   // key embeddings -> ws_eo [key][32]
    int k = tid;
    float x0 = -1.f + (float)(k>>4)*(2.f/15.f);
    float x1 = -1.f + (float)(k&15)*(2.f/15.f);
    float acc[32];
    #pragma unroll
    for (int e=0;e<32;e++) acc[e] = bk2[e];
    for (int j=0;j<128;j++) {
      float hj = fmaxf(fmaf(x0, Wk1[j], fmaf(x1, Wk1[128+j], bk1[j])), 0.f);
      #pragma unroll
      for (int u=0;u<8;u++) {
        float4 w = *(const float4*)&Wk2[j*32+u*4];
        acc[u*4+0] = fmaf(hj, w.x, acc[u*4+0]);
        acc[u*4+1] = fmaf(hj, w.y, acc[u*4+1]);
        acc[u*4+2] = fmaf(hj, w.z, acc[u*4+2]);
        acc[u*4+3] = fmaf(hj, w.w, acc[u*4+3]);
      }
    }
    #pragma unroll
    for (int e=0;e<32;e++) ws_eo[k*32+e] = __float2bfloat16(acc[e]);
  } else if (role == 2) {   // Wq2 [256h][32e] -> ws_w2t [e][h]
    int k = tid;
    #pragma unroll
    for (int u=0;u<8;u++) {
      float4 w = *(const float4*)&Wq2[k*32+u*4];
      ws_w2t[(u*4+0)*256+k] = __float2bfloat16(w.x);
      ws_w2t[(u*4+1)*256+k] = __float2bfloat16(w.y);
      ws_w2t[(u*4+2)*256+k] = __float2bfloat16(w.z);
      ws_w2t[(u*4+3)*256+k] = __float2bfloat16(w.w);
    }
  } else if (role == 3) {   // Wq1 [15][256] -> ws_w1t [h][32] with bias row k=15
    int h = tid;
    bf16 row[32];
    #pragma unroll
    for (int i=0;i<15;i++) row[i] = __float2bfloat16(Wq1[i*256+h]);
    row[15] = __float2bfloat16(bq1[h]);
    #pragma unroll
    for (int i=16;i<32;i++) row[i] = __float2bfloat16(0.f);
    #pragma unroll
    for (int i=0;i<32;i++) ws_w1t[h*32+i] = row[i];
  } else {                  // Wa1 [32e][64u] -> ws_wa1t [u][e]
    if (tid < 64) {
      #pragma unroll
      for (int e=0;e<32;e++) ws_wa1t[tid*32+e] = __float2bfloat16(Wa1[e*64+tid]);
    }
  }
}

// ---------------- k_main: wave-independent MFMA pipeline, barrier-free n-loop -------
// grid (96 q-tiles, 32 b), 4 waves; wave w handles n = w, w+4.
// Frag layouts: A[m=l15][k=quad*8+j], B[k=quad*8+j][n=l15], D[m=quad*4+r][n=l15].
// Two-pass logits max (no S[16][4] live array -> no scratch spill). eo2 == eo at
// runtime but is a distinct parameter so GVN cannot CSE pass-2's MFMAs into pass 1.
template<bool PRE>
__global__ void __launch_bounds__(256, 4)
k_main(const float* __restrict__ vc, const bf16* __restrict__ vbf_,
       const float* __restrict__ pose_o, const float* __restrict__ pose_q,
       const bf16* __restrict__ ws_eo_, const bf16* __restrict__ ws_eo2_,
       const bf16* __restrict__ ws_w2t_,
       const bf16* __restrict__ ws_w1t_, const bf16* __restrict__ ws_wa1t_,
       const float* __restrict__ bq2,
       const float* __restrict__ ba1, const float* __restrict__ Wa2,
       const float* __restrict__ ba2,
       float* __restrict__ out) {
  // per-wave slice: s_h/s_p union [16 q][264] bf16 (8448 B) + s_eq [32 e][20 q] (1280 B)
  __shared__ __align__(16) __bf16 s_wun[4][4864];
  __shared__ float s_pt[8][12];
  __shared__ float s_bw[128];   // ba1[0..63], Wa2[64..127]

  const __bf16* vbf  = (const __bf16*)vbf_;
  const __bf16* eo   = (const __bf16*)ws_eo_;
  const __bf16* eo2  = (const __bf16*)ws_eo2_;
  const __bf16* w2t  = (const __bf16*)ws_w2t_;
  const __bf16* w1t  = (const __bf16*)ws_w1t_;
  const __bf16* wa1t = (const __bf16*)ws_wa1t_;

  const int tid  = threadIdx.x;
  const int w    = tid >> 6;
  const int lane = tid & 63;
  const int quad = lane >> 4;
  const int l15  = lane & 15;
  const int b    = blockIdx.y;
  const int qt0  = blockIdx.x * 16;

  __bf16* s_h  = &s_wun[w][0];      // [q][264] (also s_p)
  __bf16* s_eq = &s_wun[w][4224];   // [e][20]

  if (tid < 8) {
    float mo[12], mq[12], pt[12];
    #pragma unroll
    for (int i=0;i<12;i++) mo[i] = pose_o[(b*8+tid)*12+i];
    #pragma unroll
    for (int i=0;i<12;i++) mq[i] = pose_q[b*12+i];
    relpose(mo, mq, pt);
    #pragma unroll
    for (int i=0;i<12;i++) s_pt[tid][i] = pt[i];
  }
  if (tid < 64) s_bw[tid] = ba1[tid];
  else if (tid < 128) s_bw[tid] = Wa2[tid-64];

  const float bq2a = bq2[l15], bq2b = bq2[l15+16];
  const float ba2v = ba2[0];
  const int qg = qt0 + l15;
  const float c0v = (float)(qg>>8) * 0.2f;
  const float c1v = -1.f + (float)((qg>>4)&15)*(2.f/15.f);
  const float c2v = -1.f + (float)(qg&15)*(2.f/15.f);

  float acc[8][4];
  #pragma unroll
  for (int ct=0;ct<8;ct++)
    #pragma unroll
    for (int r=0;r<4;r++) acc[ct][r] = 0.f;

  __syncthreads();

  #pragma unroll 1
  for (int ni=0; ni<2; ni++) {
    const int n  = w + ni*4;
    const int bn = b*8 + n;
    // ---- build X B-frag: B[k=in][q=l15]; k<12: pose, 12-14: code, 15: 1 (bias) ----
    bfrag Bx;
    #pragma unroll
    for (int j=0;j<8;j++) {
      int k = quad*8+j;
      float v = (k<12) ? s_pt[n][k<12?k:0]
              : (k==12) ? c0v : (k==13) ? c1v : (k==14) ? c2v : (k==15) ? 1.f : 0.f;
      Bx[j] = (__bf16)v;
    }
    // ---- phase 1: hidden^T = W1^T @ X, 16 h-tiles; packed b64 writes to s_h[q][h] --
    #pragma unroll
    for (int t=0;t<16;t++) {
      bfrag A = *(const bfrag*)&w1t[(t*16+l15)*32 + quad*8];
      ffrag C = {0.f,0.f,0.f,0.f};
      C = __builtin_amdgcn_mfma_f32_16x16x32_bf16(A, Bx, C, 0, 0, 0);
      __bf16 p[4] __attribute__((aligned(8)));
      #pragma unroll
      for (int r=0;r<4;r++) p[r] = (__bf16)fmaxf(C[r], 0.f);
      *(uint2*)&s_h[l15*264 + t*16 + quad*4] = *(const uint2*)p;
    }
    // ---- phase 2: layer2 D[q][e] = hidden @ W2; write s_eq[e][q] packed ----
    {
      ffrag Ca = {0.f,0.f,0.f,0.f}, Cb = {0.f,0.f,0.f,0.f};
      #pragma unroll
      for (int s=0;s<8;s++) {
        bfrag A  = *(const bfrag*)&s_h[l15*264 + s*32 + quad*8];
        bfrag B0 = *(const bfrag*)&w2t[l15*256 + s*32 + quad*8];
        bfrag B1 = *(const bfrag*)&w2t[(l15+16)*256 + s*32 + quad*8];
        Ca = __builtin_amdgcn_mfma_f32_16x16x32_bf16(A, B0, Ca, 0, 0, 0);
        Cb = __builtin_amdgcn_mfma_f32_16x16x32_bf16(A, B1, Cb, 0, 0, 0);
      }
      __bf16 pa[4] __attribute__((aligned(8))), pb[4] __attribute__((aligned(8)));
      #pragma unroll
      for (int r=0;r<4;r++) { pa[r] = (__bf16)(Ca[r]+bq2a); pb[r] = (__bf16)(Cb[r]+bq2b); }
      *(uint2*)&s_eq[l15*20 + quad*4]      = *(const uint2*)pa;
      *(uint2*)&s_eq[(l15+16)*20 + quad*4] = *(const uint2*)pb;
    }
    // ---- emb_q B-frag (k=e, n=q), reused by logits (both passes) + mask ----
    bfrag Bq;
    #pragma unroll
    for (int j=0;j<8;j++) Bq[j] = s_eq[(quad*8+j)*20 + l15];
    // ---- phase 3 pass 1: logits D[key][q], track max only ----
    float mx = -1e30f;
    #pragma unroll
    for (int t=0;t<16;t++) {
      bfrag A = *(const bfrag*)&eo[(t*16+l15)*32 + quad*8];
      ffrag C = {0.f,0.f,0.f,0.f};
      C = __builtin_amdgcn_mfma_f32_16x16x32_bf16(A, Bq, C, 0, 0, 0);
      mx = fmaxf(mx, fmaxf(fmaxf(C[0],C[1]), fmaxf(C[2],C[3])));
    }
    mx = fmaxf(mx, __shfl_xor(mx, 16));
    mx = fmaxf(mx, __shfl_xor(mx, 32));
    // ---- phase 3 pass 2: recompute (via eo2, no CSE), exp, store P bf16 ----
    float sum = 0.f;
    #pragma unroll
    for (int t=0;t<16;t++) {
      bfrag A = *(const bfrag*)&eo2[(t*16+l15)*32 + quad*8];
      ffrag C = {0.f,0.f,0.f,0.f};
      C = __builtin_amdgcn_mfma_f32_16x16x32_bf16(A, Bq, C, 0, 0, 0);
      __bf16 p[4] __attribute__((aligned(8)));
      #pragma unroll
      for (int r=0;r<4;r++) { float e = __expf(C[r]-mx); sum += e; p[r] = (__bf16)e; }
      *(uint2*)&s_h[l15*264 + t*16 + quad*4] = *(const uint2*)p;   // s_p union
    }
    sum += __shfl_xor(sum, 16);
    sum += __shfl_xor(sum, 32);
    // ---- mask D[u][q], 4 u-tiles ----
    float msum = 0.f;
    #pragma unroll
    for (int t=0;t<4;t++) {
      bfrag A = *(const bfrag*)&wa1t[(t*16+l15)*32 + quad*8];
      ffrag C = {0.f,0.f,0.f,0.f};
      C = __builtin_amdgcn_mfma_f32_16x16x32_bf16(A, Bq, C, 0, 0, 0);
      #pragma unroll
      for (int r=0;r<4;r++) {
        int u = t*16 + quad*4 + r;
        msum += fmaxf(C[r] + s_bw[u], 0.f) * s_bw[64+u];
      }
    }
    msum += __shfl_xor(msum, 16);
    msum += __shfl_xor(msum, 32);
    const float rs = sigmoidf_(msum + ba2v) / sum;
    // ---- phase 4: vatt D[c][q] = V^T @ P^T ----
    bfrag Bp[8];
    #pragma unroll
    for (int s=0;s<8;s++) Bp[s] = *(const bfrag*)&s_h[l15*264 + s*32 + quad*8];
    #pragma unroll 2
    for (int ct=0;ct<8;ct++) {
      ffrag Cv = {0.f,0.f,0.f,0.f};
      #pragma unroll
      for (int s=0;s<8;s++) {
        bfrag Av;
        if (PRE) {
          Av = *(const bfrag*)&vbf[((size_t)bn<<15) + (ct*16+l15)*256 + s*32 + quad*8];
        } else {
          const float* p0 = &vc[((size_t)bn<<15) + (ct*16+l15)*256 + s*32 + quad*8];
          float4 a0 = *(const float4*)p0, a1 = *(const float4*)(p0+4);
          Av[0]=(__bf16)a0.x; Av[1]=(__bf16)a0.y; Av[2]=(__bf16)a0.z; Av[3]=(__bf16)a0.w;
          Av[4]=(__bf16)a1.x; Av[5]=(__bf16)a1.y; Av[6]=(__bf16)a1.z; Av[7]=(__bf16)a1.w;
        }
        Cv = __builtin_amdgcn_mfma_f32_16x16x32_bf16(Av, Bp[s], Cv, 0, 0, 0);
      }
      #pragma unroll
      for (int r=0;r<4;r++) acc[ct][r] = fmaf(rs, Cv[r], acc[ct][r]);
    }
  }
  // ---- epilogue: wave partials -> LDS f32 [q][132], cross-wave sum, store ----
  {
    float* s_of = (float*)&s_wun[w][0];
    #pragma unroll
    for (int ct=0;ct<8;ct++) {
      float4 v = make_float4(acc[ct][0], acc[ct][1], acc[ct][2], acc[ct][3]);
      *(float4*)&s_of[l15*132 + ct*16 + quad*4] = v;
    }
  }
  __syncthreads();
  {
    const int c = tid >> 1, qh = (tid & 1) * 8;
    float o[8];
    #pragma unroll
    for (int j=0;j<8;j++) {
      float s = 0.f;
      #pragma unroll
      for (int ww=0;ww<4;ww++) s += ((const float*)&s_wun[ww][0])[(qh+j)*132 + c];
      o[j] = sigmoidf_(s);
    }
    float* dst = &out[(size_t)b*196608 + (size_t)c*1536 + qt0 + qh];
    *(float4*)dst     = make_float4(o[0],o[1],o[2],o[3]);
    *(float4*)(dst+4) = make_float4(o[4],o[5],o[6],o[7]);
  }
}

extern "C" void kernel_launch(void* const* d_in, const int* in_sizes, int n_in,
                              void* d_out, int out_size, void* d_ws, size_t ws_size,
                              hipStream_t stream) {
  const float* view_cell = (const float*)d_in[0];
  const float* pose_o = (const float*)d_in[1];
  const float* pose_q = (const float*)d_in[2];
  const float* Wk1 = (const float*)d_in[3];
  const float* bk1 = (const float*)d_in[4];
  const float* Wk2 = (const float*)d_in[5];
  const float* bk2 = (const float*)d_in[6];
  const float* Wq1 = (const float*)d_in[7];
  const float* bq1 = (const float*)d_in[8];
  const float* Wq2 = (const float*)d_in[9];
  const float* bq2 = (const float*)d_in[10];
  const float* Wa1 = (const float*)d_in[11];
  const float* ba1 = (const float*)d_in[12];
  const float* Wa2 = (const float*)d_in[13];
  const float* ba2 = (const float*)d_in[14];

  float* out = (float*)d_out;
  float* out_qo = out + 6291456;
  float* out_qq = out + 6291456 + 1792;

  bf16* ws_eo   = (bf16*)((char*)d_ws + WS_EO);
  bf16* ws_w2t  = (bf16*)((char*)d_ws + WS_W2T);
  bf16* ws_w1t  = (bf16*)((char*)d_ws + WS_W1T);
  bf16* ws_wa1t = (bf16*)((char*)d_ws + WS_WA1T);
  bf16* ws_vbf  = (bf16*)((char*)d_ws + WS_VBF);

  const bool pre = ws_size >= (size_t)(WS_VBF + 256u*128u*256u*2u);
  const int vblocks = pre ? 4096 : 0;

  hipLaunchKernelGGL(k_prep, dim3(vblocks + 5), dim3(256), 0, stream,
                     view_cell, ws_vbf, pose_o, pose_q, Wk1, bk1, Wk2, bk2,
                     Wq1, bq1, Wq2, Wa1, out_qo, out_qq,
                     ws_eo, ws_w2t, ws_w1t, ws_wa1t, vblocks);

  if (pre) {
    hipLaunchKernelGGL((k_main<true>), dim3(96, 32), dim3(256), 0, stream,
                       view_cell, ws_vbf, pose_o, pose_q, ws_eo, ws_eo, ws_w2t,
                       ws_w1t, ws_wa1t, bq2, ba1, Wa2, ba2, out);
  } else {
    hipLaunchKernelGGL((k_main<false>), dim3(96, 32), dim3(256), 0, stream,
                       view_cell, ws_vbf, pose_o, pose_q, ws_eo, ws_eo, ws_w2t,
                       ws_w1t, ws_wa1t, bq2, ba1, Wa2, ba2, out);
  }
}

// Round 8
// 255.308 us; speedup vs baseline: 3.3517x; 3.3517x over previous
//
#include <hip/hip_runtime.h>
#include <hip/hip_bf16.h>

using bf16 = __hip_bfloat16;
typedef __bf16 bfrag __attribute__((ext_vector_type(8)));
typedef float  ffrag __attribute__((ext_vector_type(4)));

// Problem: B=32, N=8, Q=1536, K=256, CELL=128, EMB=32. Inputs f32, outputs f32.
// workspace layout (bytes)
#define WS_EO    0         // emb_o bf16 [256 key][32 e]                16 KB
#define WS_W2T   16384     // Wq2^T bf16 [32 e][256 h]                  16 KB
#define WS_W1T   32768     // Wq1^T bf16 [256 h][32 in-pad] (+bias k15) 16 KB
#define WS_WA1T  49152     // Wa1^T bf16 [64 u][32 e]                    4 KB
#define WS_VBF   65536     // view_cell bf16 [256 bn][128 c][256 k]     16 MB (optional)

__device__ __forceinline__ float sigmoidf_(float x){ return 1.f/(1.f+__expf(-x)); }

__device__ __forceinline__ void relpose(const float* mo, const float* mq, float* o) {
  float a=mo[0],bb=mo[1],c=mo[2], d=mo[4],e=mo[5],f=mo[6], g=mo[8],h=mo[9],i9=mo[10];
  float A = e*i9-f*h, Bc = f*g-d*i9, C = d*h-e*g;
  float inv = 1.f/(a*A + bb*Bc + c*C);
  float r00=A*inv,  r01=(c*h-bb*i9)*inv, r02=(bb*f-c*e)*inv;
  float r10=Bc*inv, r11=(a*i9-c*g)*inv,  r12=(c*d-a*f)*inv;
  float r20=C*inv,  r21=(bb*g-a*h)*inv,  r22=(a*e-bb*d)*inv;
  float tx = mq[3]-mo[3], ty = mq[7]-mo[7], tz = mq[11]-mo[11];
  o[0]=r00*mq[0]+r01*mq[4]+r02*mq[8];  o[1]=r00*mq[1]+r01*mq[5]+r02*mq[9];
  o[2]=r00*mq[2]+r01*mq[6]+r02*mq[10]; o[3]=r00*tx+r01*ty+r02*tz;
  o[4]=r10*mq[0]+r11*mq[4]+r12*mq[8];  o[5]=r10*mq[1]+r11*mq[5]+r12*mq[9];
  o[6]=r10*mq[2]+r11*mq[6]+r12*mq[10]; o[7]=r10*tx+r11*ty+r12*tz;
  o[8]=r20*mq[0]+r21*mq[4]+r22*mq[8];  o[9]=r20*mq[1]+r21*mq[5]+r22*mq[9];
  o[10]=r20*mq[2]+r21*mq[6]+r22*mq[10]; o[11]=r20*tx+r21*ty+r22*tz;
}

__device__ __forceinline__ void quat7(const float* m, float* o) {
  float m00=m[0], m01=m[1], m02=m[2];
  float m10=m[4], m11=m[5], m12=m[6];
  float m20=m[8], m21=m[9], m22=m[10];
  float t,q0,q1,q2,q3;
  if (m22 < 0.f) {
    if (m00 > m11) { t=1.f+m00-m11-m22; q0=t;        q1=m01+m10; q2=m20+m02; q3=m12-m21; }
    else           { t=1.f-m00+m11-m22; q0=m01+m10; q1=t;        q2=m12+m21; q3=m20-m02; }
  } else {
    if (m00 < -m11){ t=1.f-m00-m11+m22; q0=m20+m02; q1=m12+m21; q2=t;        q3=m01-m10; }
    else           { t=1.f+m00+m11+m22; q0=m12-m21; q1=m20-m02; q2=m01-m10; q3=t;        }
  }
  float s = 0.5f / sqrtf(t);
  o[0]=m[3]; o[1]=m[7]; o[2]=m[11];
  o[3]=q0*s; o[4]=q1*s; o[5]=q2*s; o[6]=q3*s;
}

// ---------------- single prep kernel: vconv blocks + 5 parallel 1-block roles --------
__global__ void k_prep(const float* __restrict__ vc, bf16* __restrict__ vbf,
                       const float* __restrict__ pose_o, const float* __restrict__ pose_q,
                       const float* __restrict__ Wk1, const float* __restrict__ bk1,
                       const float* __restrict__ Wk2, const float* __restrict__ bk2,
                       const float* __restrict__ Wq1, const float* __restrict__ bq1,
                       const float* __restrict__ Wq2, const float* __restrict__ Wa1,
                       float* __restrict__ out_qo, float* __restrict__ out_qq,
                       bf16* __restrict__ ws_eo, bf16* __restrict__ ws_w2t,
                       bf16* __restrict__ ws_w1t, bf16* __restrict__ ws_wa1t,
                       int vblocks) {
  const int bid = blockIdx.x, tid = threadIdx.x;
  if (bid < vblocks) {   // view_cell f32 -> bf16
    int idx = (bid*256 + tid)*8;
    float4 a = *(const float4*)&vc[idx];
    float4 b = *(const float4*)&vc[idx+4];
    __bf16 o[8] __attribute__((aligned(16)));
    o[0]=(__bf16)a.x; o[1]=(__bf16)a.y; o[2]=(__bf16)a.z; o[3]=(__bf16)a.w;
    o[4]=(__bf16)b.x; o[5]=(__bf16)b.y; o[6]=(__bf16)b.z; o[7]=(__bf16)b.w;
    *(uint4*)&vbf[idx] = *(const uint4*)o;
    return;
  }
  const int role = bid - vblocks;
  if (role == 0) {          // quaternion outputs
    float mo[12];
    #pragma unroll
    for (int i=0;i<12;i++) mo[i] = pose_o[tid*12+i];
    float q7[7]; quat7(mo, q7);
    #pragma unroll
    for (int i=0;i<7;i++) out_qo[tid*7+i] = q7[i];
    if (tid < 32) {
      float mq[12];
      #pragma unroll
      for (int i=0;i<12;i++) mq[i] = pose_q[tid*12+i];
      float q7b[7]; quat7(mq, q7b);
      #pragma unroll
      for (int i=0;i<7;i++) out_qq[tid*7+i] = q7b[i];
    }
  } else if (role == 1) {   // key embeddings -> ws_eo [key][32]
    int k = tid;
    float x0 = -1.f + (float)(k>>4)*(2.f/15.f);
    float x1 = -1.f + (float)(k&15)*(2.f/15.f);
    float acc[32];
    #pragma unroll
    for (int e=0;e<32;e++) acc[e] = bk2[e];
    for (int j=0;j<128;j++) {
      float hj = fmaxf(fmaf(x0, Wk1[j], fmaf(x1, Wk1[128+j], bk1[j])), 0.f);
      #pragma unroll
      for (int u=0;u<8;u++) {
        float4 w = *(const float4*)&Wk2[j*32+u*4];
        acc[u*4+0] = fmaf(hj, w.x, acc[u*4+0]);
        acc[u*4+1] = fmaf(hj, w.y, acc[u*4+1]);
        acc[u*4+2] = fmaf(hj, w.z, acc[u*4+2]);
        acc[u*4+3] = fmaf(hj, w.w, acc[u*4+3]);
      }
    }
    #pragma unroll
    for (int e=0;e<32;e++) ws_eo[k*32+e] = __float2bfloat16(acc[e]);
  } else if (role == 2) {   // Wq2 [256h][32e] -> ws_w2t [e][h]
    int k = tid;
    #pragma unroll
    for (int u=0;u<8;u++) {
      float4 w = *(const float4*)&Wq2[k*32+u*4];
      ws_w2t[(u*4+0)*256+k] = __float2bfloat16(w.x);
      ws_w2t[(u*4+1)*256+k] = __float2bfloat16(w.y);
      ws_w2t[(u*4+2)*256+k] = __float2bfloat16(w.z);
      ws_w2t[(u*4+3)*256+k] = __float2bfloat16(w.w);
    }
  } else if (role == 3) {   // Wq1 [15][256] -> ws_w1t [h][32] with bias row k=15, 16..31 = 0
    int h = tid;
    bf16 row[32];
    #pragma unroll
    for (int i=0;i<15;i++) row[i] = __float2bfloat16(Wq1[i*256+h]);
    row[15] = __float2bfloat16(bq1[h]);
    #pragma unroll
    for (int i=16;i<32;i++) row[i] = __float2bfloat16(0.f);
    #pragma unroll
    for (int i=0;i<32;i++) ws_w1t[h*32+i] = row[i];
  } else {                  // Wa1 [32e][64u] -> ws_wa1t [u][e]
    if (tid < 64) {
      #pragma unroll
      for (int e=0;e<32;e++) ws_wa1t[tid*32+e] = __float2bfloat16(Wa1[e*64+tid]);
    }
  }
}

// ---------------- k_main: phase-split MFMA pipeline, QT=32, 4 barriers/n ------------
// grid (48 q-tiles of 32, 32 b), 4 waves. Frag layouts (gfx950 16x16x32_bf16):
//   A[m=l15][k=quad*8+j], B[k=quad*8+j][n=l15], D[m=quad*4+r][n=l15].
template<bool PRE>
__global__ void __launch_bounds__(256, 3)
k_main(const float* __restrict__ vc, const bf16* __restrict__ vbf_,
       const float* __restrict__ pose_o, const float* __restrict__ pose_q,
       const bf16* __restrict__ ws_eo_, const bf16* __restrict__ ws_w2t_,
       const bf16* __restrict__ ws_w1t_, const bf16* __restrict__ ws_wa1t_,
       const float* __restrict__ bq2,
       const float* __restrict__ ba1, const float* __restrict__ Wa2,
       const float* __restrict__ ba2,
       float* __restrict__ out) {
  __shared__ __align__(16) __bf16 s_h[32*264];    // hidden [q][h]      16896 B
  __shared__ __align__(16) __bf16 s_p[32*264];    // P exp  [q][key]    16896 B
  __shared__ __align__(16) __bf16 s_eqT[32*40];   // emb_q  [q][e]       2560 B
  __shared__ float s_pt[8][12];
  __shared__ float s_bw[128];        // ba1[0..63], Wa2[64..127]
  __shared__ float s_redA[2][16][4]; // mask partials [qs][q][w]
  __shared__ float s_redB[2][16][4]; // max partials
  __shared__ float s_redC[2][16][4]; // exp-sum partials
  // total ~38.8 KB -> 4 blocks/CU LDS-wise

  const __bf16* vbf  = (const __bf16*)vbf_;
  const __bf16* eo   = (const __bf16*)ws_eo_;
  const __bf16* w2t  = (const __bf16*)ws_w2t_;
  const __bf16* w1t  = (const __bf16*)ws_w1t_;
  const __bf16* wa1t = (const __bf16*)ws_wa1t_;

  const int tid  = threadIdx.x;
  const int w    = tid >> 6;
  const int lane = tid & 63;
  const int quad = lane >> 4;
  const int l15  = lane & 15;
  const int b    = blockIdx.y;
  const int qt0  = blockIdx.x * 32;

  // ---- staging ----
  if (tid < 8) {
    float mo[12], mq[12], pt[12];
    #pragma unroll
    for (int i=0;i<12;i++) mo[i] = pose_o[(b*8+tid)*12+i];
    #pragma unroll
    for (int i=0;i<12;i++) mq[i] = pose_q[b*12+i];
    relpose(mo, mq, pt);
    #pragma unroll
    for (int i=0;i<12;i++) s_pt[tid][i] = pt[i];
  }
  if (tid < 64) s_bw[tid] = ba1[tid];
  else if (tid < 128) s_bw[tid] = Wa2[tid-64];
  __syncthreads();

  // ---- hoisted n-invariant fragments / scalars ----
  bfrag w1A[4], eoA[4], waA;
  #pragma unroll
  for (int t=0;t<4;t++) {
    w1A[t] = *(const bfrag*)&w1t[((w*4+t)*16+l15)*32 + quad*8];
    eoA[t] = *(const bfrag*)&eo[((w*4+t)*16+l15)*32 + quad*8];
  }
  waA = *(const bfrag*)&wa1t[(w*16+l15)*32 + quad*8];
  const int   qs2 = w & 1, et = w >> 1;              // layer-2 combo
  const float bq2v = bq2[et*16 + l15];
  float ba1r[4], wa2r[4];
  #pragma unroll
  for (int r=0;r<4;r++) { ba1r[r] = s_bw[w*16+quad*4+r]; wa2r[r] = s_bw[64+w*16+quad*4+r]; }
  const float ba2v = ba2[0];
  float c012[2][3];
  #pragma unroll
  for (int qs=0;qs<2;qs++) {
    int qg = qt0 + qs*16 + l15;
    c012[qs][0] = (float)(qg>>8) * 0.2f;
    c012[qs][1] = -1.f + (float)((qg>>4)&15)*(2.f/15.f);
    c012[qs][2] = -1.f + (float)(qg&15)*(2.f/15.f);
  }

  float acc[2][2][4];   // [ct][qs][r]
  #pragma unroll
  for (int ct=0;ct<2;ct++)
    #pragma unroll
    for (int qs=0;qs<2;qs++)
      #pragma unroll
      for (int r=0;r<4;r++) acc[ct][qs][r] = 0.f;

  #pragma unroll 1
  for (int n=0; n<8; n++) {
    const int bn = b*8 + n;
    // ---- phase 1: hidden D[h][q] = W1^T @ X, K=32 (one MFMA), 4 h-tiles/wave ----
    {
      bfrag Bx[2];
      #pragma unroll
      for (int qs=0;qs<2;qs++) {
        #pragma unroll
        for (int j=0;j<8;j++) {
          int k = quad*8+j;
          float v = (k<12) ? s_pt[n][k<12?k:0]
                  : (k==12) ? c012[qs][0] : (k==13) ? c012[qs][1]
                  : (k==14) ? c012[qs][2] : (k==15) ? 1.f : 0.f;
          Bx[qs][j] = (__bf16)v;
        }
      }
      #pragma unroll
      for (int t=0;t<4;t++) {
        #pragma unroll
        for (int qs=0;qs<2;qs++) {
          ffrag C = {0.f,0.f,0.f,0.f};
          C = __builtin_amdgcn_mfma_f32_16x16x32_bf16(w1A[t], Bx[qs], C, 0, 0, 0);
          __bf16 p[4] __attribute__((aligned(8)));
          #pragma unroll
          for (int r=0;r<4;r++) p[r] = (__bf16)fmaxf(C[r], 0.f);
          *(uint2*)&s_h[(qs*16+l15)*264 + (w*4+t)*16 + quad*4] = *(const uint2*)p;
        }
      }
    }
    __syncthreads();                                   // B1
    // ---- phase 2: layer2 D[q][e] = hidden @ W2, full K=256; combo (qs2, et) ----
    {
      ffrag C2 = {0.f,0.f,0.f,0.f};
      #pragma unroll
      for (int s=0;s<8;s++) {
        bfrag A  = *(const bfrag*)&s_h[(qs2*16+l15)*264 + s*32 + quad*8];
        bfrag Bw = *(const bfrag*)&w2t[(et*16+l15)*256 + s*32 + quad*8];
        C2 = __builtin_amdgcn_mfma_f32_16x16x32_bf16(A, Bw, C2, 0, 0, 0);
      }
      #pragma unroll
      for (int r=0;r<4;r++)
        s_eqT[(qs2*16+quad*4+r)*40 + et*16 + l15] = (__bf16)(C2[r] + bq2v);
    }
    __syncthreads();                                   // B2
    // ---- phase 3: logits D[key][q] (4 key-tiles/wave) + mask D[u][q] (1 u-tile) ----
    bfrag Bq[2];
    Bq[0] = *(const bfrag*)&s_eqT[l15*40 + quad*8];
    Bq[1] = *(const bfrag*)&s_eqT[(16+l15)*40 + quad*8];
    float S[2][4][4];
    #pragma unroll
    for (int t=0;t<4;t++) {
      #pragma unroll
      for (int qs=0;qs<2;qs++) {
        ffrag C = {0.f,0.f,0.f,0.f};
        C = __builtin_amdgcn_mfma_f32_16x16x32_bf16(eoA[t], Bq[qs], C, 0, 0, 0);
        #pragma unroll
        for (int r=0;r<4;r++) S[qs][t][r] = C[r];
      }
    }
    #pragma unroll
    for (int qs=0;qs<2;qs++) {
      ffrag Cm = {0.f,0.f,0.f,0.f};
      Cm = __builtin_amdgcn_mfma_f32_16x16x32_bf16(waA, Bq[qs], Cm, 0, 0, 0);
      float msum = 0.f;
      #pragma unroll
      for (int r=0;r<4;r++) msum += fmaxf(Cm[r] + ba1r[r], 0.f) * wa2r[r];
      msum += __shfl_xor(msum, 16);
      msum += __shfl_xor(msum, 32);
      float mx = -1e30f;
      #pragma unroll
      for (int t=0;t<4;t++)
        #pragma unroll
        for (int r=0;r<4;r++) mx = fmaxf(mx, S[qs][t][r]);
      mx = fmaxf(mx, __shfl_xor(mx, 16));
      mx = fmaxf(mx, __shfl_xor(mx, 32));
      if (quad == 0) { s_redA[qs][l15][w] = msum; s_redB[qs][l15][w] = mx; }
    }
    __syncthreads();                                   // B3
    #pragma unroll
    for (int qs=0;qs<2;qs++) {
      float rmax = fmaxf(fmaxf(s_redB[qs][l15][0], s_redB[qs][l15][1]),
                         fmaxf(s_redB[qs][l15][2], s_redB[qs][l15][3]));
      float sum = 0.f;
      #pragma unroll
      for (int t=0;t<4;t++) {
        __bf16 p[4] __attribute__((aligned(8)));
        #pragma unroll
        for (int r=0;r<4;r++) { float e = __expf(S[qs][t][r]-rmax); sum += e; p[r] = (__bf16)e; }
        *(uint2*)&s_p[(qs*16+l15)*264 + (w*4+t)*16 + quad*4] = *(const uint2*)p;
      }
      sum += __shfl_xor(sum, 16);
      sum += __shfl_xor(sum, 32);
      if (quad == 0) s_redC[qs][l15][w] = sum;
    }
    __syncthreads();                                   // B4
    float rs[2];
    #pragma unroll
    for (int qs=0;qs<2;qs++) {
      float msumT = ba2v + s_redA[qs][l15][0] + s_redA[qs][l15][1]
                         + s_redA[qs][l15][2] + s_redA[qs][l15][3];
      float ssum  = s_redC[qs][l15][0] + s_redC[qs][l15][1]
                  + s_redC[qs][l15][2] + s_redC[qs][l15][3];
      rs[qs] = sigmoidf_(msumT) / ssum;
    }
    // ---- phase 4: vatt D[c][q] = V^T @ P^T; wave w: c-tiles 2w,2w+1 × 2 qs ----
    {
      ffrag Cv[2][2];
      #pragma unroll
      for (int ct=0;ct<2;ct++)
        #pragma unroll
        for (int qs=0;qs<2;qs++) Cv[ct][qs] = (ffrag){0.f,0.f,0.f,0.f};
      #pragma unroll
      for (int s=0;s<8;s++) {
        bfrag Bp0 = *(const bfrag*)&s_p[l15*264 + s*32 + quad*8];
        bfrag Bp1 = *(const bfrag*)&s_p[(16+l15)*264 + s*32 + quad*8];
        #pragma unroll
        for (int ct=0;ct<2;ct++) {
          bfrag Av;
          if (PRE) {
            Av = *(const bfrag*)&vbf[((size_t)bn<<15) + ((2*w+ct)*16+l15)*256 + s*32 + quad*8];
          } else {
            const float* p0 = &vc[((size_t)bn<<15) + ((2*w+ct)*16+l15)*256 + s*32 + quad*8];
            float4 a0 = *(const float4*)p0, a1 = *(const float4*)(p0+4);
            Av[0]=(__bf16)a0.x; Av[1]=(__bf16)a0.y; Av[2]=(__bf16)a0.z; Av[3]=(__bf16)a0.w;
            Av[4]=(__bf16)a1.x; Av[5]=(__bf16)a1.y; Av[6]=(__bf16)a1.z; Av[7]=(__bf16)a1.w;
          }
          Cv[ct][0] = __builtin_amdgcn_mfma_f32_16x16x32_bf16(Av, Bp0, Cv[ct][0], 0, 0, 0);
          Cv[ct][1] = __builtin_amdgcn_mfma_f32_16x16x32_bf16(Av, Bp1, Cv[ct][1], 0, 0, 0);
        }
      }
      #pragma unroll
      for (int ct=0;ct<2;ct++)
        #pragma unroll
        for (int qs=0;qs<2;qs++)
          #pragma unroll
          for (int r=0;r<4;r++) acc[ct][qs][r] = fmaf(rs[qs], Cv[ct][qs][r], acc[ct][qs][r]);
    }
    __syncthreads();                                   // B5: protect s_h/s_p/s_red reuse
  }
  // ---- epilogue: direct coalesced stores (16 lanes consecutive q = 64 B) ----
  #pragma unroll
  for (int ct=0;ct<2;ct++) {
    #pragma unroll
    for (int qs=0;qs<2;qs++) {
      #pragma unroll
      for (int r=0;r<4;r++) {
        int c = (2*w+ct)*16 + quad*4 + r;
        out[(size_t)b*196608 + (size_t)c*1536 + qt0 + qs*16 + l15] = sigmoidf_(acc[ct][qs][r]);
      }
    }
  }
}

extern "C" void kernel_launch(void* const* d_in, const int* in_sizes, int n_in,
                              void* d_out, int out_size, void* d_ws, size_t ws_size,
                              hipStream_t stream) {
  const float* view_cell = (const float*)d_in[0];
  const float* pose_o = (const float*)d_in[1];
  const float* pose_q = (const float*)d_in[2];
  const float* Wk1 = (const float*)d_in[3];
  const float* bk1 = (const float*)d_in[4];
  const float* Wk2 = (const float*)d_in[5];
  const float* bk2 = (const float*)d_in[6];
  const float* Wq1 = (const float*)d_in[7];
  const float* bq1 = (const float*)d_in[8];
  const float* Wq2 = (const float*)d_in[9];
  const float* bq2 = (const float*)d_in[10];
  const float* Wa1 = (const float*)d_in[11];
  const float* ba1 = (const float*)d_in[12];
  const float* Wa2 = (const float*)d_in[13];
  const float* ba2 = (const float*)d_in[14];

  float* out = (float*)d_out;
  float* out_qo = out + 6291456;
  float* out_qq = out + 6291456 + 1792;

  bf16* ws_eo   = (bf16*)((char*)d_ws + WS_EO);
  bf16* ws_w2t  = (bf16*)((char*)d_ws + WS_W2T);
  bf16* ws_w1t  = (bf16*)((char*)d_ws + WS_W1T);
  bf16* ws_wa1t = (bf16*)((char*)d_ws + WS_WA1T);
  bf16* ws_vbf  = (bf16*)((char*)d_ws + WS_VBF);

  const bool pre = ws_size >= (size_t)(WS_VBF + 256u*128u*256u*2u);
  const int vblocks = pre ? 4096 : 0;

  hipLaunchKernelGGL(k_prep, dim3(vblocks + 5), dim3(256), 0, stream,
                     view_cell, ws_vbf, pose_o, pose_q, Wk1, bk1, Wk2, bk2,
                     Wq1, bq1, Wq2, Wa1, out_qo, out_qq,
                     ws_eo, ws_w2t, ws_w1t, ws_wa1t, vblocks);

  if (pre) {
    hipLaunchKernelGGL((k_main<true>), dim3(48, 32), dim3(256), 0, stream,
                       view_cell, ws_vbf, pose_o, pose_q, ws_eo, ws_w2t,
                       ws_w1t, ws_wa1t, bq2, ba1, Wa2, ba2, out);
  } else {
    hipLaunchKernelGGL((k_main<false>), dim3(48, 32), dim3(256), 0, stream,
                       view_cell, ws_vbf, pose_o, pose_q, ws_eo, ws_w2t,
                       ws_w1t, ws_wa1t, bq2, ba1, Wa2, ba2, out);
  }
}